// Round 2
// baseline (362.690 us; speedup 1.0000x reference)
//
#include <hip/hip_runtime.h>
#include <hip/hip_bf16.h>

// Round 2: identical to round 1 (container was unresponsive; no signal).

typedef __attribute__((ext_vector_type(4))) float floatx4;
typedef __attribute__((ext_vector_type(8))) short short8;
typedef __attribute__((ext_vector_type(8))) unsigned short ushortx8;

#define K1 2048
#define N1 1024
#define K2 1024
#define N2 1024

__device__ __forceinline__ unsigned short f2bf(float f) {
  __hip_bfloat16 h = __float2bfloat16(f);
  return __builtin_bit_cast(unsigned short, h);
}

__device__ __forceinline__ void gload_lds16(const void* g, void* l) {
  __builtin_amdgcn_global_load_lds(
      (__attribute__((address_space(1))) void*)const_cast<void*>(g),
      (__attribute__((address_space(3))) void*)l, 16, 0, 0);
}

__global__ void cvt_bf16_kernel(const float* __restrict__ src,
                                unsigned short* __restrict__ dst, int n4) {
  int i = blockIdx.x * blockDim.x + threadIdx.x;
  if (i >= n4) return;
  float4 f = reinterpret_cast<const float4*>(src)[i];
  ushort4 o;
  o.x = f2bf(f.x); o.y = f2bf(f.y); o.z = f2bf(f.z); o.w = f2bf(f.w);
  reinterpret_cast<ushort4*>(dst)[i] = o;
}

// GEMM1: h[m][n] = gelu( sum_k tok[idx[m]][k] * W1[n][k] + b1[n] ), h in bf16
__global__ __launch_bounds__(256) void gemm1_gelu_kernel(
    const int* __restrict__ idxs, const float* __restrict__ tok,
    const unsigned short* __restrict__ W1b, const float* __restrict__ b1,
    unsigned short* __restrict__ hout) {
  // LDS layout: [kg 0..3][row 0..127][8 bf16] -> conflict-free ds_read_b128
  __shared__ unsigned short Asub[4096];
  __shared__ unsigned short Bsub[4096];
  const int t = threadIdx.x;
  const int bid = blockIdx.x;
  const int bm = bid >> 3, bn = bid & 7;
  const int brow0 = bm * 128, bcol0 = bn * 128;

  // A gather staging: thread t loads 64B (16 fp32) of row (t&127), half (t>>7)
  const int arow = t & 127;
  const int ahalf = t >> 7;
  const float* aptr = tok + (size_t)idxs[brow0 + arow] * K1 + ahalf * 16;
  unsigned short* awr0 = &Asub[(ahalf * 2) * 1024 + arow * 8];
  unsigned short* awr1 = &Asub[(ahalf * 2 + 1) * 1024 + arow * 8];

  // B staging via global_load_lds: chunk c = j*256 + w*64 + lane -> (kg=c>>7, n=c&127)
  const int w = t >> 6, lane = t & 63;
  const int c0 = w * 64 + lane, c1 = c0 + 256;
  const unsigned short* bp0 = W1b + (size_t)(bcol0 + (c0 & 127)) * K1 + (c0 >> 7) * 8;
  const unsigned short* bp1 = W1b + (size_t)(bcol0 + (c1 & 127)) * K1 + (c1 >> 7) * 8;
  unsigned short* bl0 = &Bsub[(w * 64) * 8];        // wave-uniform base
  unsigned short* bl1 = &Bsub[(w * 64 + 256) * 8];

  // fragment addressing
  const int wm = w >> 1, wn = w & 1;
  const int fr = lane & 15, kg = lane >> 4;
  const int aoff = kg * 1024 + (wm * 64 + fr) * 8;
  const int boff = kg * 1024 + (wn * 64 + fr) * 8;

  floatx4 acc[4][4] = {};

  for (int k0 = 0; k0 < K1; k0 += 32) {
    const float4 a0 = *reinterpret_cast<const float4*>(aptr + k0);
    const float4 a1 = *reinterpret_cast<const float4*>(aptr + k0 + 4);
    const float4 a2 = *reinterpret_cast<const float4*>(aptr + k0 + 8);
    const float4 a3 = *reinterpret_cast<const float4*>(aptr + k0 + 12);
    __syncthreads();  // previous compute done
    ushortx8 u0, u1;
    u0[0] = f2bf(a0.x); u0[1] = f2bf(a0.y); u0[2] = f2bf(a0.z); u0[3] = f2bf(a0.w);
    u0[4] = f2bf(a1.x); u0[5] = f2bf(a1.y); u0[6] = f2bf(a1.z); u0[7] = f2bf(a1.w);
    u1[0] = f2bf(a2.x); u1[1] = f2bf(a2.y); u1[2] = f2bf(a2.z); u1[3] = f2bf(a2.w);
    u1[4] = f2bf(a3.x); u1[5] = f2bf(a3.y); u1[6] = f2bf(a3.z); u1[7] = f2bf(a3.w);
    *reinterpret_cast<ushortx8*>(awr0) = u0;
    *reinterpret_cast<ushortx8*>(awr1) = u1;
    gload_lds16(bp0 + k0, bl0);
    gload_lds16(bp1 + k0, bl1);
    __syncthreads();  // staging complete (barrier drains vmcnt+lgkm)
    short8 af[4], bfr[4];
#pragma unroll
    for (int i = 0; i < 4; ++i)
      af[i] = *reinterpret_cast<const short8*>(&Asub[aoff + i * 128]);
#pragma unroll
    for (int j = 0; j < 4; ++j)
      bfr[j] = *reinterpret_cast<const short8*>(&Bsub[boff + j * 128]);
#pragma unroll
    for (int i = 0; i < 4; ++i)
#pragma unroll
      for (int j = 0; j < 4; ++j)
        acc[i][j] = __builtin_amdgcn_mfma_f32_16x16x32_bf16(af[i], bfr[j], acc[i][j], 0, 0, 0);
  }

  // epilogue: bias + exact GELU -> bf16
  const int er = brow0 + wm * 64 + (lane >> 4) * 4;
  const int ec = bcol0 + wn * 64 + fr;
#pragma unroll
  for (int j = 0; j < 4; ++j) {
    const float bv = b1[ec + j * 16];
#pragma unroll
    for (int i = 0; i < 4; ++i)
#pragma unroll
      for (int r = 0; r < 4; ++r) {
        float v = acc[i][j][r] + bv;
        v = 0.5f * v * (1.0f + erff(v * 0.70710678118654752f));
        hout[(size_t)(er + i * 16 + r) * N1 + (ec + j * 16)] = f2bf(v);
      }
  }
}

// GEMM2: out[m][n] = sum_k h[m][k] * W2[n][k] + b2[n], fp32 out
__global__ __launch_bounds__(256) void gemm2_kernel(
    const unsigned short* __restrict__ hb, const unsigned short* __restrict__ W2b,
    const float* __restrict__ b2, float* __restrict__ out) {
  __shared__ unsigned short Asub[4096];
  __shared__ unsigned short Bsub[4096];
  const int t = threadIdx.x;
  const int bid = blockIdx.x;
  const int bm = bid >> 3, bn = bid & 7;
  const int brow0 = bm * 128, bcol0 = bn * 128;
  const int w = t >> 6, lane = t & 63;
  const int c0 = w * 64 + lane, c1 = c0 + 256;
  const unsigned short* ap0 = hb + (size_t)(brow0 + (c0 & 127)) * K2 + (c0 >> 7) * 8;
  const unsigned short* ap1 = hb + (size_t)(brow0 + (c1 & 127)) * K2 + (c1 >> 7) * 8;
  const unsigned short* bp0 = W2b + (size_t)(bcol0 + (c0 & 127)) * K2 + (c0 >> 7) * 8;
  const unsigned short* bp1 = W2b + (size_t)(bcol0 + (c1 & 127)) * K2 + (c1 >> 7) * 8;
  unsigned short* al0 = &Asub[(w * 64) * 8];
  unsigned short* al1 = &Asub[(w * 64 + 256) * 8];
  unsigned short* bl0 = &Bsub[(w * 64) * 8];
  unsigned short* bl1 = &Bsub[(w * 64 + 256) * 8];

  const int wm = w >> 1, wn = w & 1;
  const int fr = lane & 15, kg = lane >> 4;
  const int aoff = kg * 1024 + (wm * 64 + fr) * 8;
  const int boff = kg * 1024 + (wn * 64 + fr) * 8;

  floatx4 acc[4][4] = {};

  for (int k0 = 0; k0 < K2; k0 += 32) {
    __syncthreads();  // previous compute done
    gload_lds16(ap0 + k0, al0);
    gload_lds16(ap1 + k0, al1);
    gload_lds16(bp0 + k0, bl0);
    gload_lds16(bp1 + k0, bl1);
    __syncthreads();  // staging complete
    short8 af[4], bfr[4];
#pragma unroll
    for (int i = 0; i < 4; ++i)
      af[i] = *reinterpret_cast<const short8*>(&Asub[aoff + i * 128]);
#pragma unroll
    for (int j = 0; j < 4; ++j)
      bfr[j] = *reinterpret_cast<const short8*>(&Bsub[boff + j * 128]);
#pragma unroll
    for (int i = 0; i < 4; ++i)
#pragma unroll
      for (int j = 0; j < 4; ++j)
        acc[i][j] = __builtin_amdgcn_mfma_f32_16x16x32_bf16(af[i], bfr[j], acc[i][j], 0, 0, 0);
  }

  const int er = brow0 + wm * 64 + (lane >> 4) * 4;
  const int ec = bcol0 + wn * 64 + fr;
#pragma unroll
  for (int j = 0; j < 4; ++j) {
    const float bv = b2[ec + j * 16];
#pragma unroll
    for (int i = 0; i < 4; ++i)
#pragma unroll
      for (int r = 0; r < 4; ++r)
        out[(size_t)(er + i * 16 + r) * N2 + (ec + j * 16)] = acc[i][j][r] + bv;
  }
}

extern "C" void kernel_launch(void* const* d_in, const int* in_sizes, int n_in,
                              void* d_out, int out_size, void* d_ws, size_t ws_size,
                              hipStream_t stream) {
  const int* idxs = (const int*)d_in[0];
  const float* tok = (const float*)d_in[1];
  const float* W1 = (const float*)d_in[2];
  const float* b1 = (const float*)d_in[3];
  const float* W2 = (const float*)d_in[4];
  const float* b2 = (const float*)d_in[5];
  float* out = (float*)d_out;

  unsigned short* W1b = (unsigned short*)d_ws;                          // 4 MB
  unsigned short* W2b = (unsigned short*)((char*)d_ws + (4u << 20));    // 2 MB
  unsigned short* hbuf = (unsigned short*)((char*)d_ws + (6u << 20));   // 32 MB

  cvt_bf16_kernel<<<2048, 256, 0, stream>>>(W1, W1b, 524288);   // 1024*2048/4
  cvt_bf16_kernel<<<1024, 256, 0, stream>>>(W2, W2b, 262144);   // 1024*1024/4
  gemm1_gelu_kernel<<<1024, 256, 0, stream>>>(idxs, tok, W1b, b1, hbuf);
  gemm2_kernel<<<1024, 256, 0, stream>>>(hbuf, W2b, b2, out);
}

// Round 3
// 286.936 us; speedup vs baseline: 1.2640x; 1.2640x over previous
//
#include <hip/hip_runtime.h>
#include <hip/hip_bf16.h>

typedef __attribute__((ext_vector_type(4))) float floatx4;
typedef __attribute__((ext_vector_type(8))) short short8;
typedef __attribute__((ext_vector_type(8))) unsigned short ushortx8;

#define K1 2048
#define N1 1024
#define K2 1024
#define N2 1024

__device__ __forceinline__ unsigned short f2bf(float f) {
  __hip_bfloat16 h = __float2bfloat16(f);
  return __builtin_bit_cast(unsigned short, h);
}

__device__ __forceinline__ void gload_lds16(const void* g, void* l) {
  __builtin_amdgcn_global_load_lds(
      (__attribute__((address_space(1))) void*)const_cast<void*>(g),
      (__attribute__((address_space(3))) void*)l, 16, 0, 0);
}

__global__ void cvt_bf16_kernel(const float* __restrict__ src,
                                unsigned short* __restrict__ dst, int n4) {
  int i = blockIdx.x * blockDim.x + threadIdx.x;
  if (i >= n4) return;
  float4 f = reinterpret_cast<const float4*>(src)[i];
  ushort4 o;
  o.x = f2bf(f.x); o.y = f2bf(f.y); o.z = f2bf(f.z); o.w = f2bf(f.w);
  reinterpret_cast<ushort4*>(dst)[i] = o;
}

// Gather + fp32->bf16: xb[row][k] = bf16(tok[idxs[row]][k]). One block per row.
__global__ __launch_bounds__(256) void gather_cvt_kernel(
    const int* __restrict__ idxs, const float* __restrict__ tok,
    unsigned short* __restrict__ xb) {
  const int row = blockIdx.x;
  const float* src = tok + (size_t)idxs[row] * K1;
  unsigned short* dst = xb + (size_t)row * K1;
  const int o = threadIdx.x * 8;
  const float4 f0 = *reinterpret_cast<const float4*>(src + o);
  const float4 f1 = *reinterpret_cast<const float4*>(src + o + 4);
  ushortx8 u;
  u[0] = f2bf(f0.x); u[1] = f2bf(f0.y); u[2] = f2bf(f0.z); u[3] = f2bf(f0.w);
  u[4] = f2bf(f1.x); u[5] = f2bf(f1.y); u[6] = f2bf(f1.z); u[7] = f2bf(f1.w);
  *reinterpret_cast<ushortx8*>(dst + o) = u;
}

// GEMM1 (main path): h = gelu(xb @ W1^T + b1), all-bf16 staging, dbuf, XCD swizzle.
__global__ __launch_bounds__(256) void gemm1_gelu_kernel(
    const unsigned short* __restrict__ xb, const unsigned short* __restrict__ W1b,
    const float* __restrict__ b1, unsigned short* __restrict__ hout) {
  __shared__ unsigned short Asub[2][4096];
  __shared__ unsigned short Bsub[2][4096];
  const int t = threadIdx.x;
  int bid = blockIdx.x;
  bid = (bid & 7) * 128 + (bid >> 3);  // XCD x owns bm in [x*16, x*16+16)
  const int bm = bid >> 3, bn = bid & 7;
  const int brow0 = bm * 128, bcol0 = bn * 128;
  const int w = t >> 6, lane = t & 63;
  const int c0 = w * 64 + lane, c1 = c0 + 256;
  const unsigned short* ap0 = xb + (size_t)(brow0 + (c0 & 127)) * K1 + (c0 >> 7) * 8;
  const unsigned short* ap1 = xb + (size_t)(brow0 + (c1 & 127)) * K1 + (c1 >> 7) * 8;
  const unsigned short* bp0 = W1b + (size_t)(bcol0 + (c0 & 127)) * K1 + (c0 >> 7) * 8;
  const unsigned short* bp1 = W1b + (size_t)(bcol0 + (c1 & 127)) * K1 + (c1 >> 7) * 8;
  const int l0 = (w * 64) * 8, l1 = (w * 64 + 256) * 8;

  const int wm = w >> 1, wn = w & 1;
  const int fr = lane & 15, kg = lane >> 4;
  const int aoff = kg * 1024 + (wm * 64 + fr) * 8;
  const int boff = kg * 1024 + (wn * 64 + fr) * 8;

  floatx4 acc[4][4] = {};

  // prologue: stage tile 0
  gload_lds16(ap0, &Asub[0][l0]);
  gload_lds16(ap1, &Asub[0][l1]);
  gload_lds16(bp0, &Bsub[0][l0]);
  gload_lds16(bp1, &Bsub[0][l1]);
  __syncthreads();

  for (int it = 0; it < K1 / 32; ++it) {
    const int cur = it & 1;
    if (it < K1 / 32 - 1) {  // prefetch next tile; stays in flight during MFMA
      const int k0 = (it + 1) * 32;
      gload_lds16(ap0 + k0, &Asub[cur ^ 1][l0]);
      gload_lds16(ap1 + k0, &Asub[cur ^ 1][l1]);
      gload_lds16(bp0 + k0, &Bsub[cur ^ 1][l0]);
      gload_lds16(bp1 + k0, &Bsub[cur ^ 1][l1]);
    }
    short8 af[4], bfr[4];
#pragma unroll
    for (int i = 0; i < 4; ++i)
      af[i] = *reinterpret_cast<const short8*>(&Asub[cur][aoff + i * 128]);
#pragma unroll
    for (int j = 0; j < 4; ++j)
      bfr[j] = *reinterpret_cast<const short8*>(&Bsub[cur][boff + j * 128]);
#pragma unroll
    for (int i = 0; i < 4; ++i)
#pragma unroll
      for (int j = 0; j < 4; ++j)
        acc[i][j] = __builtin_amdgcn_mfma_f32_16x16x32_bf16(af[i], bfr[j], acc[i][j], 0, 0, 0);
    __syncthreads();  // drains vmcnt (next tile ready) + lgkm (cur reads done)
  }

  const int er = brow0 + wm * 64 + (lane >> 4) * 4;
  const int ec = bcol0 + wn * 64 + fr;
#pragma unroll
  for (int j = 0; j < 4; ++j) {
    const float bv = b1[ec + j * 16];
#pragma unroll
    for (int i = 0; i < 4; ++i)
#pragma unroll
      for (int r = 0; r < 4; ++r) {
        float v = acc[i][j][r] + bv;
        v = 0.5f * v * (1.0f + erff(v * 0.70710678118654752f));
        hout[(size_t)(er + i * 16 + r) * N1 + (ec + j * 16)] = f2bf(v);
      }
  }
}

// GEMM1 (fallback, ws too small): fused gather, single-buffer (round-2) + swizzle.
__global__ __launch_bounds__(256) void gemm1_fused_kernel(
    const int* __restrict__ idxs, const float* __restrict__ tok,
    const unsigned short* __restrict__ W1b, const float* __restrict__ b1,
    unsigned short* __restrict__ hout) {
  __shared__ unsigned short Asub[4096];
  __shared__ unsigned short Bsub[4096];
  const int t = threadIdx.x;
  int bid = blockIdx.x;
  bid = (bid & 7) * 128 + (bid >> 3);
  const int bm = bid >> 3, bn = bid & 7;
  const int brow0 = bm * 128, bcol0 = bn * 128;
  const int arow = t & 127;
  const int ahalf = t >> 7;
  const float* aptr = tok + (size_t)idxs[brow0 + arow] * K1 + ahalf * 16;
  unsigned short* awr0 = &Asub[(ahalf * 2) * 1024 + arow * 8];
  unsigned short* awr1 = &Asub[(ahalf * 2 + 1) * 1024 + arow * 8];
  const int w = t >> 6, lane = t & 63;
  const int c0 = w * 64 + lane, c1 = c0 + 256;
  const unsigned short* bp0 = W1b + (size_t)(bcol0 + (c0 & 127)) * K1 + (c0 >> 7) * 8;
  const unsigned short* bp1 = W1b + (size_t)(bcol0 + (c1 & 127)) * K1 + (c1 >> 7) * 8;
  unsigned short* bl0 = &Bsub[(w * 64) * 8];
  unsigned short* bl1 = &Bsub[(w * 64 + 256) * 8];
  const int wm = w >> 1, wn = w & 1;
  const int fr = lane & 15, kg = lane >> 4;
  const int aoff = kg * 1024 + (wm * 64 + fr) * 8;
  const int boff = kg * 1024 + (wn * 64 + fr) * 8;
  floatx4 acc[4][4] = {};
  for (int k0 = 0; k0 < K1; k0 += 32) {
    const float4 a0 = *reinterpret_cast<const float4*>(aptr + k0);
    const float4 a1 = *reinterpret_cast<const float4*>(aptr + k0 + 4);
    const float4 a2 = *reinterpret_cast<const float4*>(aptr + k0 + 8);
    const float4 a3 = *reinterpret_cast<const float4*>(aptr + k0 + 12);
    __syncthreads();
    ushortx8 u0, u1;
    u0[0] = f2bf(a0.x); u0[1] = f2bf(a0.y); u0[2] = f2bf(a0.z); u0[3] = f2bf(a0.w);
    u0[4] = f2bf(a1.x); u0[5] = f2bf(a1.y); u0[6] = f2bf(a1.z); u0[7] = f2bf(a1.w);
    u1[0] = f2bf(a2.x); u1[1] = f2bf(a2.y); u1[2] = f2bf(a2.z); u1[3] = f2bf(a2.w);
    u1[4] = f2bf(a3.x); u1[5] = f2bf(a3.y); u1[6] = f2bf(a3.z); u1[7] = f2bf(a3.w);
    *reinterpret_cast<ushortx8*>(awr0) = u0;
    *reinterpret_cast<ushortx8*>(awr1) = u1;
    gload_lds16(bp0 + k0, bl0);
    gload_lds16(bp1 + k0, bl1);
    __syncthreads();
    short8 af[4], bfr[4];
#pragma unroll
    for (int i = 0; i < 4; ++i)
      af[i] = *reinterpret_cast<const short8*>(&Asub[aoff + i * 128]);
#pragma unroll
    for (int j = 0; j < 4; ++j)
      bfr[j] = *reinterpret_cast<const short8*>(&Bsub[boff + j * 128]);
#pragma unroll
    for (int i = 0; i < 4; ++i)
#pragma unroll
      for (int j = 0; j < 4; ++j)
        acc[i][j] = __builtin_amdgcn_mfma_f32_16x16x32_bf16(af[i], bfr[j], acc[i][j], 0, 0, 0);
  }
  const int er = brow0 + wm * 64 + (lane >> 4) * 4;
  const int ec = bcol0 + wn * 64 + fr;
#pragma unroll
  for (int j = 0; j < 4; ++j) {
    const float bv = b1[ec + j * 16];
#pragma unroll
    for (int i = 0; i < 4; ++i)
#pragma unroll
      for (int r = 0; r < 4; ++r) {
        float v = acc[i][j][r] + bv;
        v = 0.5f * v * (1.0f + erff(v * 0.70710678118654752f));
        hout[(size_t)(er + i * 16 + r) * N1 + (ec + j * 16)] = f2bf(v);
      }
  }
}

// GEMM2: out = h @ W2^T + b2 (fp32 out), dbuf, XCD swizzle.
__global__ __launch_bounds__(256) void gemm2_kernel(
    const unsigned short* __restrict__ hb, const unsigned short* __restrict__ W2b,
    const float* __restrict__ b2, float* __restrict__ out) {
  __shared__ unsigned short Asub[2][4096];
  __shared__ unsigned short Bsub[2][4096];
  const int t = threadIdx.x;
  int bid = blockIdx.x;
  bid = (bid & 7) * 128 + (bid >> 3);
  const int bm = bid >> 3, bn = bid & 7;
  const int brow0 = bm * 128, bcol0 = bn * 128;
  const int w = t >> 6, lane = t & 63;
  const int c0 = w * 64 + lane, c1 = c0 + 256;
  const unsigned short* ap0 = hb + (size_t)(brow0 + (c0 & 127)) * K2 + (c0 >> 7) * 8;
  const unsigned short* ap1 = hb + (size_t)(brow0 + (c1 & 127)) * K2 + (c1 >> 7) * 8;
  const unsigned short* bp0 = W2b + (size_t)(bcol0 + (c0 & 127)) * K2 + (c0 >> 7) * 8;
  const unsigned short* bp1 = W2b + (size_t)(bcol0 + (c1 & 127)) * K2 + (c1 >> 7) * 8;
  const int l0 = (w * 64) * 8, l1 = (w * 64 + 256) * 8;

  const int wm = w >> 1, wn = w & 1;
  const int fr = lane & 15, kg = lane >> 4;
  const int aoff = kg * 1024 + (wm * 64 + fr) * 8;
  const int boff = kg * 1024 + (wn * 64 + fr) * 8;

  floatx4 acc[4][4] = {};

  gload_lds16(ap0, &Asub[0][l0]);
  gload_lds16(ap1, &Asub[0][l1]);
  gload_lds16(bp0, &Bsub[0][l0]);
  gload_lds16(bp1, &Bsub[0][l1]);
  __syncthreads();

  for (int it = 0; it < K2 / 32; ++it) {
    const int cur = it & 1;
    if (it < K2 / 32 - 1) {
      const int k0 = (it + 1) * 32;
      gload_lds16(ap0 + k0, &Asub[cur ^ 1][l0]);
      gload_lds16(ap1 + k0, &Asub[cur ^ 1][l1]);
      gload_lds16(bp0 + k0, &Bsub[cur ^ 1][l0]);
      gload_lds16(bp1 + k0, &Bsub[cur ^ 1][l1]);
    }
    short8 af[4], bfr[4];
#pragma unroll
    for (int i = 0; i < 4; ++i)
      af[i] = *reinterpret_cast<const short8*>(&Asub[cur][aoff + i * 128]);
#pragma unroll
    for (int j = 0; j < 4; ++j)
      bfr[j] = *reinterpret_cast<const short8*>(&Bsub[cur][boff + j * 128]);
#pragma unroll
    for (int i = 0; i < 4; ++i)
#pragma unroll
      for (int j = 0; j < 4; ++j)
        acc[i][j] = __builtin_amdgcn_mfma_f32_16x16x32_bf16(af[i], bfr[j], acc[i][j], 0, 0, 0);
    __syncthreads();
  }

  const int er = brow0 + wm * 64 + (lane >> 4) * 4;
  const int ec = bcol0 + wn * 64 + fr;
#pragma unroll
  for (int j = 0; j < 4; ++j) {
    const float bv = b2[ec + j * 16];
#pragma unroll
    for (int i = 0; i < 4; ++i)
#pragma unroll
      for (int r = 0; r < 4; ++r)
        out[(size_t)(er + i * 16 + r) * N2 + (ec + j * 16)] = acc[i][j][r] + bv;
  }
}

extern "C" void kernel_launch(void* const* d_in, const int* in_sizes, int n_in,
                              void* d_out, int out_size, void* d_ws, size_t ws_size,
                              hipStream_t stream) {
  const int* idxs = (const int*)d_in[0];
  const float* tok = (const float*)d_in[1];
  const float* W1 = (const float*)d_in[2];
  const float* b1 = (const float*)d_in[3];
  const float* W2 = (const float*)d_in[4];
  const float* b2 = (const float*)d_in[5];
  float* out = (float*)d_out;

  unsigned short* W1b = (unsigned short*)d_ws;                        // 4 MB
  unsigned short* W2b = (unsigned short*)((char*)d_ws + (4u << 20));  // 2 MB

  cvt_bf16_kernel<<<2048, 256, 0, stream>>>(W1, W1b, 524288);
  cvt_bf16_kernel<<<1024, 256, 0, stream>>>(W2, W2b, 262144);

  const size_t need = (size_t)(4 + 2 + 64 + 32) << 20;  // 102 MB
  if (ws_size >= need) {
    unsigned short* xb = (unsigned short*)((char*)d_ws + (6u << 20));     // 64 MB
    unsigned short* hbuf = (unsigned short*)((char*)d_ws + (70u << 20));  // 32 MB
    gather_cvt_kernel<<<16384, 256, 0, stream>>>(idxs, tok, xb);
    gemm1_gelu_kernel<<<1024, 256, 0, stream>>>(xb, W1b, b1, hbuf);
    gemm2_kernel<<<1024, 256, 0, stream>>>(hbuf, W2b, b2, out);
  } else {
    unsigned short* hbuf = (unsigned short*)((char*)d_ws + (6u << 20));   // 32 MB
    gemm1_fused_kernel<<<1024, 256, 0, stream>>>(idxs, tok, W1b, b1, hbuf);
    gemm2_kernel<<<1024, 256, 0, stream>>>(hbuf, W2b, b2, out);
  }
}